// Round 17
// baseline (94.291 us; speedup 1.0000x reference)
//
#include <hip/hip_runtime.h>

#define B_    128
#define I_    4608
#define O_    10
#define D_    16
#define NCHUNKS 2304      // I_/2
#define NIB   32          // i-blocks; 144 i = 72 chunks each
#define CPB   72          // chunks per i-block: 72/8 waves = 9 chunks/wave
#define CHH   2560        // halves per prepped chunk: 5 p * 64 lane * 8
#define UPS   20480       // units per set: 128 b * 10 o * 16 d
#define PSTRIDE ((long)UPS * NIB)   // floats per parts set (2.62 MB)

typedef _Float16 f16x2 __attribute__((ext_vector_type(2)));
typedef _Float16 f16x4 __attribute__((ext_vector_type(4)));
typedef _Float16 f16x8 __attribute__((ext_vector_type(8)));
typedef float    f32x4 __attribute__((ext_vector_type(4)));
typedef __fp16   pk16x2 __attribute__((ext_vector_type(2)));
typedef unsigned int uint2v __attribute__((ext_vector_type(2)));

__device__ __forceinline__ f16x4 pack4(float a, float b, float c, float d) {
    union { f16x4 v; pk16x2 p[2]; } u;
    u.p[0] = __builtin_amdgcn_cvt_pkrtz(a, b);
    u.p[1] = __builtin_amdgcn_cvt_pkrtz(c, d);
    return u.v;
}
__device__ __forceinline__ f16x2 splat_h2(float a) {
    union { f16x2 v; pk16x2 p; } u;
    u.p = __builtin_amdgcn_cvt_pkrtz(a, a);
    return u.v;
}
__device__ __forceinline__ float sum32(const float* p) {
    const float4* p4 = (const float4*)p;
    float4 a = p4[0], b = p4[1], c = p4[2], d = p4[3];
    float4 e = p4[4], f = p4[5], g = p4[6], h = p4[7];
    float s0 = (a.x+a.y)+(a.z+a.w), s1 = (b.x+b.y)+(b.z+b.w);
    float s2 = (c.x+c.y)+(c.z+c.w), s3 = (d.x+d.y)+(d.z+d.w);
    float s4 = (e.x+e.y)+(e.z+e.w), s5 = (f.x+f.y)+(f.z+f.w);
    float s6 = (g.x+g.y)+(g.z+g.w), s7 = (h.x+h.y)+(h.z+h.w);
    return ((s0+s1)+(s2+s3))+((s4+s5)+(s6+s7));
}

// ---------------------------------------------------------------------------
// MFMA routing pass (R16-verified main loop). Grid 256 = 32 ib x 8 bg,
// XCD-grouped, 1 block/CU, 9 chunks/wave. parts layout: [unit][ib] f32,
// unit = (b*10+o)*16+d (ib innermost -> head-reduce reads contiguous 128B).
// ITER 0: prep-fused (reads fp32 W coalesced, packs P-frags in-register,
//         bg==0 blocks persist them to pw). Uniform c (pre=0.1 at final).
// ITER 1: head-reduce parts0 -> v = squash(0.1*S0) in LDS; logits path.
// ITER 2: head-reduce parts0,parts1 -> v = sq(0.1*S0)+sq(S1); logits path.
// Logits: Wt via identity-MFMA transpose; u = mfma(Wt,v); bd = in-lane dot
// + permlane32_swap; softmax over o. End: LDS tree -> parts write.
// ---------------------------------------------------------------------------
template<int ITER>
__global__ __launch_bounds__(512, 2)
void pass_kernel(const float* __restrict__ x,      // [128][4608][8]
                 const float* __restrict__ w,      // [10][4608][16][8] (ITER 0)
                 _Float16* __restrict__ pwW,       // pw write (ITER 0, bg==0)
                 const _Float16* __restrict__ pw,  // pw read (ITER 1/2)
                 const float* __restrict__ parts0, // prior sets (heads)
                 const float* __restrict__ parts1,
                 float* __restrict__ partsOut)     // this pass's output set
{
    __shared__ float red[4 * 2560];   // 40 KB; head uses [0, 5472)

    const int tid  = threadIdx.x;
    const int lane = tid & 63;
    const int wv   = tid >> 6;
    const int bl   = lane & 15;
    const int g    = lane >> 4;
    const int u    = blockIdx.x;
    const int xcd  = u & 7, s = u >> 3;            // s: 0..31
    const int ib   = xcd * 4 + (s & 3);            // same-XCD blocks share ib range
    const int bg   = s >> 2;                       // 0..7
    const int c0   = ib * CPB;
    const int iloc = g & 1, kq = g >> 1;
    const int b0   = bg * 16 + bl;
    const int bb   = bg * 16;                      // block b base
    const bool wrt = (ITER == 0) && (bg == 0);

    // identity B-frag: I[K=4g+j][col=bl] = (4g+j == bl)
    f16x4 idf;
#pragma unroll
    for (int j = 0; j < 4; ++j) idf[j] = (_Float16)((bl == 4 * g + j) ? 1.f : 0.f);

    // ---- head: build v in LDS from parts sets (ITER >= 1) ----
    float* a0  = red;               // [16][161] padded (b-stride 161)
    float* sc0 = red + 2576;        // [160]
    float* a1  = red + 2736;        // [16][161]
    float* sc1 = red + 5312;        // [160]
    f16x4 vf[O_];
    if (ITER >= 1) {
#pragma unroll
        for (int q = 0; q < 5; ++q) {
            const int uq   = tid + q * 512;        // 0..2559: (bloc*160 + o*16+d)
            const int bloc = uq / 160, rem = uq - bloc * 160;
            const long gofs = ((long)bb * 160 + uq) * NIB;
            a0[bloc * 161 + rem] = 0.1f * sum32(parts0 + gofs);
            if (ITER == 2) a1[bloc * 161 + rem] = sum32(parts1 + gofs);
        }
        __syncthreads();
        if (tid < 160) {
            const int base = (tid / 10) * 161 + (tid % 10) * 16;
            float n2 = 0.f;
#pragma unroll
            for (int d = 0; d < 16; ++d) { const float t = a0[base + d]; n2 = fmaf(t, t, n2); }
            sc0[tid] = n2 / ((1.f + n2) * (sqrtf(n2) + 1e-8f));
            if (ITER == 2) {
                float m2 = 0.f;
#pragma unroll
                for (int d = 0; d < 16; ++d) { const float t = a1[base + d]; m2 = fmaf(t, t, m2); }
                sc1[tid] = m2 / ((1.f + m2) * (sqrtf(m2) + 1e-8f));
            }
        }
        __syncthreads();
#pragma unroll
        for (int o = 0; o < O_; ++o) {
            const int base = bl * 161 + o * 16 + 4 * g;
            const float s0v = sc0[bl * 10 + o];
            float v0 = a0[base] * s0v, v1 = a0[base + 1] * s0v;
            float v2 = a0[base + 2] * s0v, v3 = a0[base + 3] * s0v;
            if (ITER == 2) {
                const float s1v = sc1[bl * 10 + o];
                v0 = fmaf(a1[base], s1v, v0);     v1 = fmaf(a1[base + 1], s1v, v1);
                v2 = fmaf(a1[base + 2], s1v, v2); v3 = fmaf(a1[base + 3], s1v, v3);
            }
            vf[o] = pack4(v0, v1, v2, v3);
        }
        __syncthreads();   // head LDS reads done before tree reuses red
    }

    f32x4 S[O_];
#pragma unroll
    for (int o = 0; o < O_; ++o) S[o] = (f32x4)(0.f);

    const long lofs = (long)lane * 8;
    const int  wofs = bl * 8 + kq * 4;             // within W[o][i]: d*8 + k
    auto fragp = [&](int c, int p) {
        return (const f16x8*)(pw + (long)c * CHH + p * 512 + lofs);
    };
    auto xp = [&](int c) {
        return (const float4*)(x + ((long)b0 * I_ + 2 * c + iloc) * 8 + kq * 4);
    };
    auto wload = [&](int c, f16x8 (&f)[5]) {
        const long iofs = (long)(2 * c + iloc) * 128 + wofs;
#pragma unroll
        for (int p = 0; p < 5; ++p) {
            const float4 w0 = *(const float4*)(w + (long)(2 * p)     * (I_ * 128) + iofs);
            const float4 w1 = *(const float4*)(w + (long)(2 * p + 1) * (I_ * 128) + iofs);
            union { f16x8 v8; f16x4 h[2]; } u2;
            u2.h[0] = pack4(w0.x, w0.y, w0.z, w0.w);
            u2.h[1] = pack4(w1.x, w1.y, w1.z, w1.w);
            f[p] = u2.v8;
        }
    };

    int c = c0 + wv;
    f16x8 f1[5];
    float4 xqC, xqN;
    if (ITER == 0) wload(c, f1);
    else {
#pragma unroll
        for (int p = 0; p < 5; ++p) f1[p] = *fragp(c, p);
    }
    xqC = *xp(c);

    for (int t5 = 0; t5 < 9; ++t5) {
        int cn = c + 8; if (cn > NCHUNKS - 1) cn = NCHUNKS - 1;
        xqN = *xp(cn);

        float cs[O_];
        if (ITER >= 1) {
#pragma unroll
            for (int p = 0; p < 5; ++p) {
                f16x4 pe, po;
                pe[0]=f1[p][0]; pe[1]=f1[p][1]; pe[2]=f1[p][2]; pe[3]=f1[p][3];
                po[0]=f1[p][4]; po[1]=f1[p][5]; po[2]=f1[p][6]; po[3]=f1[p][7];
                const f32x4 te = __builtin_amdgcn_mfma_f32_16x16x16f16(pe, idf, (f32x4)(0.f), 0, 0, 0);
                const f32x4 to = __builtin_amdgcn_mfma_f32_16x16x16f16(po, idf, (f32x4)(0.f), 0, 0, 0);
                const f16x4 ae = pack4(te[0], te[1], te[2], te[3]);
                const f16x4 ao = pack4(to[0], to[1], to[2], to[3]);
                const f32x4 ua = __builtin_amdgcn_mfma_f32_16x16x16f16(ae, vf[2*p],   (f32x4)(0.f), 0, 0, 0);
                const f32x4 ub = __builtin_amdgcn_mfma_f32_16x16x16f16(ao, vf[2*p+1], (f32x4)(0.f), 0, 0, 0);
                float d0 = ua[0] * xqC.x; d0 = fmaf(ua[1], xqC.y, d0);
                d0 = fmaf(ua[2], xqC.z, d0); d0 = fmaf(ua[3], xqC.w, d0);
                float d1 = ub[0] * xqC.x; d1 = fmaf(ub[1], xqC.y, d1);
                d1 = fmaf(ub[2], xqC.z, d1); d1 = fmaf(ub[3], xqC.w, d1);
                cs[2*p] = d0; cs[2*p+1] = d1;
            }
            float ssum = 0.f;
#pragma unroll
            for (int o = 0; o < O_; ++o) {
                const unsigned int tt = __float_as_uint(cs[o]);
                const uint2v sw = __builtin_amdgcn_permlane32_swap(tt, tt, false, false);
                const float e = __expf(__uint_as_float(sw[0]) + __uint_as_float(sw[1]));
                cs[o] = e; ssum += e;
            }
            const float inv = 1.f / ssum;
#pragma unroll
            for (int o = 0; o < O_; ++o) cs[o] *= inv;
        }

        union F4 { f16x4 v; f16x2 h[2]; };
        F4 xh;
        xh.v = pack4(xqC.x, xqC.y, xqC.z, xqC.w);
#pragma unroll
        for (int p = 0; p < 5; ++p) {
            f16x4 pe, po;
            pe[0]=f1[p][0]; pe[1]=f1[p][1]; pe[2]=f1[p][2]; pe[3]=f1[p][3];
            po[0]=f1[p][4]; po[1]=f1[p][5]; po[2]=f1[p][6]; po[3]=f1[p][7];
            F4 ye, yo;
            if (ITER == 0) { ye = xh; yo = xh; }
            else {
                const f16x2 ce = splat_h2(cs[2*p]);
                const f16x2 co = splat_h2(cs[2*p+1]);
                ye.h[0] = xh.h[0] * ce; ye.h[1] = xh.h[1] * ce;
                yo.h[0] = xh.h[0] * co; yo.h[1] = xh.h[1] * co;
            }
            S[2*p]   = __builtin_amdgcn_mfma_f32_16x16x16f16(pe, ye.v, S[2*p],   0, 0, 0);
            S[2*p+1] = __builtin_amdgcn_mfma_f32_16x16x16f16(po, yo.v, S[2*p+1], 0, 0, 0);
        }

        if (ITER == 0) {
            if (wrt) {
#pragma unroll
                for (int p = 0; p < 5; ++p)
                    *(f16x8*)(pwW + (long)c * CHH + p * 512 + lofs) = f1[p];
            }
            wload(cn, f1);
        } else {
#pragma unroll
            for (int p = 0; p < 5; ++p) f1[p] = *fragp(cn, p);
        }
        xqC = xqN;
        c += 8;
    }

    // ---- inter-wave tree reduction ----
    __syncthreads();
    auto slot = [&](int ww, int o) {
        return &red[ww * 2560 + o * 256 + lane * 4];
    };
#define TREE_WR(WSRC)                                                       \
    if (wv >= WSRC && wv < 2 * WSRC) {                                      \
        _Pragma("unroll") for (int o = 0; o < O_; ++o)                      \
            *(f32x4*)slot(wv - WSRC, o) = S[o];                             \
    }                                                                       \
    __syncthreads();                                                        \
    if (wv < WSRC) {                                                        \
        _Pragma("unroll") for (int o = 0; o < O_; ++o)                      \
            S[o] += *(f32x4*)slot(wv, o);                                   \
    }                                                                       \
    __syncthreads();

    TREE_WR(4)
    TREE_WR(2)
    TREE_WR(1)
#undef TREE_WR

    if (wv == 0) {
        // parts[unit][ib], unit = (b0*10+o)*16 + 4g+j
#pragma unroll
        for (int o = 0; o < O_; ++o) {
            const long base = ((long)(b0 * 10 + o) * 16 + 4 * g) * NIB + ib;
            partsOut[base]           = S[o][0];
            partsOut[base + NIB]     = S[o][1];
            partsOut[base + 2 * NIB] = S[o][2];
            partsOut[base + 3 * NIB] = S[o][3];
        }
    }
}

// ---------------------------------------------------------------------------
// Final: out = 0.3*sq(0.1*S0) + 0.3*sq(S1) + 0.4*sq(S2). Grid 1280 blocks,
// one per (b*10+o) unit; parts layout [unit][d][ib].
// ---------------------------------------------------------------------------
__global__ __launch_bounds__(256)
void final_squash(const float* __restrict__ p0, const float* __restrict__ p1,
                  const float* __restrict__ p2, float* __restrict__ out)
{
    __shared__ float red2[4][16];
    const int tid  = threadIdx.x;
    const int lane = tid & 63;
    const int wv   = tid >> 6;
    const int unit = blockIdx.x;        // (b*10 + o)
    const int d    = tid & 15;
    const int pg   = tid >> 4;          // 0..15

    const float pres[3] = {0.1f, 1.f, 1.f};
    const float ks[3]   = {0.3f, 0.3f, 0.4f};
    const float* ps[3]  = {p0, p1, p2};

    float acc = 0.f;
#pragma unroll
    for (int setk = 0; setk < 3; ++setk) {
        const float* pp = ps[setk] + ((long)unit * 16 + d) * NIB + pg * 2;
        float sv = pp[0] + pp[1];
        sv += __shfl_xor(sv, 16);
        sv += __shfl_xor(sv, 32);
        if (lane < 16) red2[wv][lane] = sv;
        __syncthreads();
        if (tid < 16) {
            float tot = (red2[0][tid] + red2[1][tid]) + (red2[2][tid] + red2[3][tid]);
            tot *= pres[setk];
            float n2 = tot * tot;
            n2 += __shfl_xor(n2, 1);
            n2 += __shfl_xor(n2, 2);
            n2 += __shfl_xor(n2, 4);
            n2 += __shfl_xor(n2, 8);
            const float n = sqrtf(n2);
            acc = fmaf(ks[setk] * (n2 / ((1.f + n2) * (n + 1e-8f))), tot, acc);
        }
        __syncthreads();
    }
    if (tid < 16) out[unit * D_ + tid] = acc;
}

// ---------------------------------------------------------------------------
extern "C" void kernel_launch(void* const* d_in, const int* in_sizes, int n_in,
                              void* d_out, int out_size, void* d_ws, size_t ws_size,
                              hipStream_t stream)
{
    const float* x = (const float*)d_in[0];   // [128,4608,8]
    const float* w = (const float*)d_in[1];   // [10,4608,16,8]
    float* out    = (float*)d_out;            // [128,10,16]
    float* parts0 = (float*)d_ws;             // 3 x 2.62 MB
    float* parts1 = parts0 + PSTRIDE;
    float* parts2 = parts1 + PSTRIDE;
    _Float16* pw  = (_Float16*)(parts2 + PSTRIDE);   // 11.8 MB P frag image

    // iter 0: uniform c (prep fused, emits pw)
    pass_kernel<0><<<256, 512, 0, stream>>>(x, w, pw, pw, parts0, parts1, parts0);
    // iter 1: head-reduce parts0 -> v0; logits; emits parts1
    pass_kernel<1><<<256, 512, 0, stream>>>(x, w, pw, pw, parts0, parts1, parts1);
    // iter 2: head-reduce parts0+parts1 -> v; logits; emits parts2
    pass_kernel<2><<<256, 512, 0, stream>>>(x, w, pw, pw, parts0, parts1, parts2);
    // final: combine all three sets
    final_squash<<<1280, 256, 0, stream>>>(parts0, parts1, parts2, out);
}

// Round 18
// 61.643 us; speedup vs baseline: 1.5296x; 1.5296x over previous
//
#include <hip/hip_runtime.h>

#define B_    128
#define I_    4608
#define O_    10
#define D_    16
#define NCHUNKS 2304      // I_/2
#define NIB   32          // i-blocks; 144 i = 72 chunks each
#define CPB   72          // chunks per i-block: 72/8 waves = 9 chunks/wave, no tail
#define CHH   2560        // halves per prepped chunk: 5 p * 64 lane * 8 (P image only)
#define PSET  20480       // floats per partial set (128*10*16)

typedef _Float16 f16x2 __attribute__((ext_vector_type(2)));
typedef _Float16 f16x4 __attribute__((ext_vector_type(4)));
typedef _Float16 f16x8 __attribute__((ext_vector_type(8)));
typedef float    f32x4 __attribute__((ext_vector_type(4)));
typedef __fp16   pk16x2 __attribute__((ext_vector_type(2)));
typedef unsigned int uint2v __attribute__((ext_vector_type(2)));

__device__ __forceinline__ f16x4 pack4(float a, float b, float c, float d) {
    union { f16x4 v; pk16x2 p[2]; } u;
    u.p[0] = __builtin_amdgcn_cvt_pkrtz(a, b);
    u.p[1] = __builtin_amdgcn_cvt_pkrtz(c, d);
    return u.v;
}
__device__ __forceinline__ f16x2 splat_h2(float a) {
    union { f16x2 v; pk16x2 p; } u;
    u.p = __builtin_amdgcn_cvt_pkrtz(a, a);
    return u.v;
}

// ---------------------------------------------------------------------------
// MFMA routing pass. Grid 256 = 32 i-blocks x 8 b-groups (16 b each),
// XCD-grouped, 1 block/CU, 9 chunks/wave exactly (R15 geometry).
// MODE 0 (prep-fused): reads raw fp32 W per chunk — coalesced: for fixed o
//   the wave's 64 lanes exactly cover the 1 KB slab W[o][2c..2c+1][*][*]
//   (lane groups g=0..3 <-> (iloc,kq) pairs). Packs P-frags in-register
//   (same cvt_pkrtz as the old prep -> bit-identical), applies, and the
//   bg==0 blocks store the f16 frags to pw for passes 1/2.
// MODE 1: reads pw f16 (R10/R15-verified); logits: Wt frag via identity-MFMA
//   transpose, u = mfma(Wt, v), bd = in-lane dot + permlane32_swap, softmax.
// End: 3-step LDS tree over waves -> parts[ib].
// ---------------------------------------------------------------------------
template<int MODE>
__global__ __launch_bounds__(512, 2)
void pass_kernel(const float* __restrict__ x,      // [128][4608][8]
                 const float* __restrict__ w,      // [10][4608][16][8] (MODE 0)
                 _Float16* __restrict__ pwW,       // pw write (MODE 0, bg==0)
                 const _Float16* __restrict__ pw,  // pw read (MODE 1)
                 const float* __restrict__ v,      // [128][10][16]
                 float* __restrict__ parts)        // [NIB][128][10][16]
{
    __shared__ float red[4 * 2560];   // 40 KB

    const int tid  = threadIdx.x;
    const int lane = tid & 63;
    const int wv   = tid >> 6;
    const int bl   = lane & 15;
    const int g    = lane >> 4;
    const int u    = blockIdx.x;
    const int xcd  = u & 7, s = u >> 3;            // s: 0..31
    const int ib   = xcd * 4 + (s & 3);            // same-XCD blocks share ib range
    const int bg   = s >> 2;                       // 0..7
    const int c0   = ib * CPB;
    const int iloc = g & 1, kq = g >> 1;
    const int b0   = bg * 16 + bl;
    const bool wrt = (MODE == 0) && (bg == 0);     // pw writer blocks

    // identity B-frag: I[K=4g+j][col=bl] = (4g+j == bl)
    f16x4 idf;
#pragma unroll
    for (int j = 0; j < 4; ++j) idf[j] = (_Float16)((bl == 4 * g + j) ? 1.f : 0.f);

    f16x4 vf[O_];
    if (MODE == 1) {
#pragma unroll
        for (int o = 0; o < O_; ++o) {
            const float4 vv = *(const float4*)(v + ((long)b0 * O_ + o) * D_ + g * 4);
            vf[o] = pack4(vv.x, vv.y, vv.z, vv.w);
        }
    }

    f32x4 S[O_];
#pragma unroll
    for (int o = 0; o < O_; ++o) S[o] = (f32x4)(0.f);

    const long lofs = (long)lane * 8;
    const int  wofs = bl * 8 + kq * 4;             // within W[o][i]: d*8 + k
    auto fragp = [&](int c, int p) {
        return (const f16x8*)(pw + (long)c * CHH + p * 512 + lofs);
    };
    auto xp = [&](int c) {
        return (const float4*)(x + ((long)b0 * I_ + 2 * c + iloc) * 8 + kq * 4);
    };
    // MODE 0: gather chunk c's P-frags straight from fp32 W (coalesced per o)
    auto wload = [&](int c, f16x8 (&f)[5]) {
        const long iofs = (long)(2 * c + iloc) * 128 + wofs;
#pragma unroll
        for (int p = 0; p < 5; ++p) {
            const float4 w0 = *(const float4*)(w + (long)(2 * p)     * (I_ * 128) + iofs);
            const float4 w1 = *(const float4*)(w + (long)(2 * p + 1) * (I_ * 128) + iofs);
            union { f16x8 v8; f16x4 h[2]; } u2;
            u2.h[0] = pack4(w0.x, w0.y, w0.z, w0.w);
            u2.h[1] = pack4(w1.x, w1.y, w1.z, w1.w);
            f[p] = u2.v8;
        }
    };

    int c = c0 + wv;
    f16x8 f1[5];
    float4 xqC, xqN;
    if (MODE == 0) wload(c, f1);
    else {
#pragma unroll
        for (int p = 0; p < 5; ++p) f1[p] = *fragp(c, p);
    }
    xqC = *xp(c);

    for (int t5 = 0; t5 < 9; ++t5) {
        int cn = c + 8; if (cn > NCHUNKS - 1) cn = NCHUNKS - 1;
        xqN = *xp(cn);

        float cs[O_];
        if (MODE == 1) {
            // logits: Wt = transpose(P) via identity MFMA; u = Wt x v;
            // bd = sum_k u*x (in-lane + permlane32_swap); softmax over o
#pragma unroll
            for (int p = 0; p < 5; ++p) {
                f16x4 pe, po;
                pe[0]=f1[p][0]; pe[1]=f1[p][1]; pe[2]=f1[p][2]; pe[3]=f1[p][3];
                po[0]=f1[p][4]; po[1]=f1[p][5]; po[2]=f1[p][6]; po[3]=f1[p][7];
                const f32x4 te = __builtin_amdgcn_mfma_f32_16x16x16f16(pe, idf, (f32x4)(0.f), 0, 0, 0);
                const f32x4 to = __builtin_amdgcn_mfma_f32_16x16x16f16(po, idf, (f32x4)(0.f), 0, 0, 0);
                const f16x4 ae = pack4(te[0], te[1], te[2], te[3]);
                const f16x4 ao = pack4(to[0], to[1], to[2], to[3]);
                const f32x4 ua = __builtin_amdgcn_mfma_f32_16x16x16f16(ae, vf[2*p],   (f32x4)(0.f), 0, 0, 0);
                const f32x4 ub = __builtin_amdgcn_mfma_f32_16x16x16f16(ao, vf[2*p+1], (f32x4)(0.f), 0, 0, 0);
                float d0 = ua[0] * xqC.x; d0 = fmaf(ua[1], xqC.y, d0);
                d0 = fmaf(ua[2], xqC.z, d0); d0 = fmaf(ua[3], xqC.w, d0);
                float d1 = ub[0] * xqC.x; d1 = fmaf(ub[1], xqC.y, d1);
                d1 = fmaf(ub[2], xqC.z, d1); d1 = fmaf(ub[3], xqC.w, d1);
                cs[2*p] = d0; cs[2*p+1] = d1;
            }
            float ssum = 0.f;
#pragma unroll
            for (int o = 0; o < O_; ++o) {
                const unsigned int tt = __float_as_uint(cs[o]);
                const uint2v sw = __builtin_amdgcn_permlane32_swap(tt, tt, false, false);
                const float e = __expf(__uint_as_float(sw[0]) + __uint_as_float(sw[1]));
                cs[o] = e; ssum += e;
            }
            const float inv = 1.f / ssum;
#pragma unroll
            for (int o = 0; o < O_; ++o) cs[o] *= inv;
        }

        union F4 { f16x4 v; f16x2 h[2]; };
        F4 xh;
        xh.v = pack4(xqC.x, xqC.y, xqC.z, xqC.w);
#pragma unroll
        for (int p = 0; p < 5; ++p) {
            f16x4 pe, po;
            pe[0]=f1[p][0]; pe[1]=f1[p][1]; pe[2]=f1[p][2]; pe[3]=f1[p][3];
            po[0]=f1[p][4]; po[1]=f1[p][5]; po[2]=f1[p][6]; po[7==7?4:0]=f1[p][4]; po[5-1]=f1[p][4]; po[0]=f1[p][4]; po[1]=f1[p][5]; po[2]=f1[p][6]; po[3]=f1[p][7];
            F4 ye, yo;
            if (MODE == 0) { ye = xh; yo = xh; }
            else {
                const f16x2 ce = splat_h2(cs[2*p]);
                const f16x2 co = splat_h2(cs[2*p+1]);
                ye.h[0] = xh.h[0] * ce; ye.h[1] = xh.h[1] * ce;
                yo.h[0] = xh.h[0] * co; yo.h[1] = xh.h[1] * co;
            }
            S[2*p]   = __builtin_amdgcn_mfma_f32_16x16x16f16(pe, ye.v, S[2*p],   0, 0, 0);
            S[2*p+1] = __builtin_amdgcn_mfma_f32_16x16x16f16(po, yo.v, S[2*p+1], 0, 0, 0);
        }

        if (MODE == 0) {
            if (wrt) {   // persist chunk c's frags for passes 1/2 (written once)
#pragma unroll
                for (int p = 0; p < 5; ++p)
                    *(f16x8*)(pwW + (long)c * CHH + p * 512 + lofs) = f1[p];
            }
            wload(cn, f1);
        } else {
#pragma unroll
            for (int p = 0; p < 5; ++p) f1[p] = *fragp(cn, p);
        }
        xqC = xqN;
        c += 8;
    }

    // ---- inter-wave tree reduction (waves covered disjoint chunks) ----
    auto slot = [&](int ww, int o) {
        return &red[ww * 2560 + o * 256 + lane * 4];
    };
#define TREE_WR(WSRC)                                                       \
    if (wv >= WSRC && wv < 2 * WSRC) {                                      \
        _Pragma("unroll") for (int o = 0; o < O_; ++o)                      \
            *(f32x4*)slot(wv - WSRC, o) = S[o];                             \
    }                                                                       \
    __syncthreads();                                                        \
    if (wv < WSRC) {                                                        \
        _Pragma("unroll") for (int o = 0; o < O_; ++o)                      \
            S[o] += *(f32x4*)slot(wv, o);                                   \
    }                                                                       \
    __syncthreads();

    TREE_WR(4)
    TREE_WR(2)
    TREE_WR(1)
#undef TREE_WR

    if (wv == 0) {
#pragma unroll
        for (int o = 0; o < O_; ++o) {
            float* pp = parts + (long)ib * PSET + ((long)b0 * O_ + o) * D_ + g * 4;
            *(f32x4*)pp = S[o];
        }
    }
}

// ---------------------------------------------------------------------------
// Reduce 32 partial sets -> s[b,o,d]; squash over d; update v_buf / out.
// Grid 1280 (one block per (b,o)).  (R15-verified)
// ---------------------------------------------------------------------------
__global__ __launch_bounds__(256)
void reduce_squash(const float* __restrict__ parts, float* __restrict__ v_buf,
                   float* __restrict__ out, float kscale, float pre, int mode)
{
    __shared__ float red2[4][16];
    const int tid  = threadIdx.x;
    const int lane = tid & 63;
    const int wv   = tid >> 6;
    const int g2   = blockIdx.x;        // (b*O + o)
    const int pg   = tid >> 4;          // 0..15
    const int d    = tid & 15;

    float s = 0.f;
#pragma unroll
    for (int k = 0; k < 2; ++k)
        s += parts[(long)(pg * 2 + k) * PSET + g2 * D_ + d];

    s += __shfl_xor(s, 16);
    s += __shfl_xor(s, 32);
    if (lane < 16) red2[wv][lane] = s;
    __syncthreads();

    if (tid < 16) {
        float tot = (red2[0][tid] + red2[1][tid]) + (red2[2][tid] + red2[3][tid]);
        tot *= pre;
        float n2 = tot * tot;
        n2 += __shfl_xor(n2, 1);
        n2 += __shfl_xor(n2, 2);
        n2 += __shfl_xor(n2, 4);
        n2 += __shfl_xor(n2, 8);
        const float n     = sqrtf(n2);
        const float scale = n2 / ((1.f + n2) * (n + 1e-8f));
        const float o_    = scale * tot;
        const int idx = g2 * D_ + tid;
        if (mode == 0)      { v_buf[idx] = o_;  out[idx]  = kscale * o_; }
        else if (mode == 1) { v_buf[idx] += o_; out[idx] += kscale * o_; }
        else                {                   out[idx] += kscale * o_; }
    }
}

// ---------------------------------------------------------------------------
extern "C" void kernel_launch(void* const* d_in, const int* in_sizes, int n_in,
                              void* d_out, int out_size, void* d_ws, size_t ws_size,
                              hipStream_t stream)
{
    const float* x = (const float*)d_in[0];   // [128,4608,8]
    const float* w = (const float*)d_in[1];   // [10,4608,16,8]
    float* out   = (float*)d_out;             // [128,10,16]
    float* parts = (float*)d_ws;                          // 32*80KB = 2.62 MB
    float* v_buf = parts + (long)NIB * PSET;              // 80 KB
    _Float16* pw = (_Float16*)(v_buf + B_ * O_ * D_);     // 11.8 MB P frag image

    // iter 0: c = 1/10 uniform (pre=0.1 in reduce); prep fused (emits pw)
    pass_kernel<0><<<256, 512, 0, stream>>>(x, w, pw, pw, v_buf, parts);
    reduce_squash<<<1280, 256, 0, stream>>>(parts, v_buf, out, 0.3f, 0.1f, 0);

    // iter 1: b1 = <out0, xh>
    pass_kernel<1><<<256, 512, 0, stream>>>(x, w, pw, pw, v_buf, parts);
    reduce_squash<<<1280, 256, 0, stream>>>(parts, v_buf, out, 0.3f, 1.0f, 1);

    // iter 2: b2 = <out0 + out1, xh>
    pass_kernel<1><<<256, 512, 0, stream>>>(x, w, pw, pw, v_buf, parts);
    reduce_squash<<<1280, 256, 0, stream>>>(parts, v_buf, out, 0.4f, 1.0f, 2);
}